// Round 9
// baseline (96.016 us; speedup 1.0000x reference)
//
#include <hip/hip_runtime.h>

#define DIM 64
#define HW 4096          // 64*64
#define NELEM 8388608.0f // 32*64*4096
#define NBLK 1024        // 128-col tiles

typedef __attribute__((ext_vector_type(8))) short short8;   // 8 x bf16
typedef __attribute__((ext_vector_type(4))) float f32x4;
typedef __attribute__((ext_vector_type(2))) float f32x2;

__device__ __forceinline__ unsigned short f2bf(float f) {
  unsigned int u = __builtin_bit_cast(unsigned int, f);
  u += 0x7fffu + ((u >> 16) & 1u);            // round-to-nearest-even
  return (unsigned short)(u >> 16);
}

__device__ __forceinline__ float wave_sum(float v) {
  #pragma unroll
  for (int off = 32; off >= 1; off >>= 1) v += __shfl_xor(v, off);
  return v;
}

// ws layout (bytes):
//  [0,      65536)  A-frags: bf16(-2*codebook), MFMA-fragment order (L2-hot)
//  [65536,  67584)  cnorm fp32 [512]
//  [67584,  71680)  per-block partial sum(x^2)      (1024 floats)
//  [75776,  79872)  per-block partial sum(min d2')  (1024 floats)

// ---------------- prep: codebook -> fragment order (once per call) ---------
__global__ void vq_prep(const float* __restrict__ CB,
                        unsigned short* __restrict__ aFg,
                        float* __restrict__ cn) {
  const int t = threadIdx.x;
  const int s = blockIdx.x * 512 + t;     // 0..4095 fragment slots
  const int chunk = s >> 7, ks = (s >> 6) & 1, ls = s & 63;
  const int code = chunk * 16 + (ls & 15);
  const int d0 = ks * 32 + (ls >> 4) * 8;
  const float* cp = CB + code * DIM + d0;
  float4 u0 = *(const float4*)cp;
  float4 u1 = *(const float4*)(cp + 4);
  short8 p;
  p[0]=(short)f2bf(-2.f*u0.x); p[1]=(short)f2bf(-2.f*u0.y);
  p[2]=(short)f2bf(-2.f*u0.z); p[3]=(short)f2bf(-2.f*u0.w);
  p[4]=(short)f2bf(-2.f*u1.x); p[5]=(short)f2bf(-2.f*u1.y);
  p[6]=(short)f2bf(-2.f*u1.z); p[7]=(short)f2bf(-2.f*u1.w);
  *(short8*)&aFg[s * 8] = p;
  if (blockIdx.x == 0) {                  // exact fp32 ||c_k||^2
    const float* c2 = CB + t * DIM;
    float sn = 0.f;
    #pragma unroll
    for (int i = 0; i < 16; ++i) {
      float4 u = *(const float4*)(c2 + i * 4);
      sn += u.x*u.x + u.y*u.y + u.z*u.z + u.w*u.w;
    }
    cn[t] = sn;
  }
}

// ---- main: 1024 blocks x 4 waves; 128-col tile; codes split across waves --
// R9: INSTRUMENTATION ROUND.  Body = byte-identical R1 (34.25us champion),
// wrapped in rep<2 (idempotent: identical k, identical stores, partials
// overwritten).  Purpose: vq_main dispatch ~58-62us rises above the 41us
// harness fills into the rocprof top-5, exposing its hbm_gbps / VALUBusy /
// MfmaUtil / FETCH / WRITE for the first time; dur_us - 34.25 also measures
// vq_main standalone.  REVERT the rep loop next round.
// NO atomics/fences (same-addr device atomics ~100us convoy, prev session).
__global__ __launch_bounds__(256, 4)
void vq_main(const float* __restrict__ X, const float* __restrict__ CB,
             const unsigned short* __restrict__ aFg,
             const float* __restrict__ cng,
             float* __restrict__ out,
             float* __restrict__ pA, float* __restrict__ pB) {
  __shared__ __align__(16) unsigned short XF[16 * 64 * 8]; // 16 KB frag-order
  __shared__ float mW[4][128];                // per-wave packed mins per col
  __shared__ float red[8];

  const int t   = threadIdx.x;
  const int bid = blockIdx.x;
  // XCD-chunked swizzle: XCD x owns logical blocks [x*128,(x+1)*128)
  const int L   = ((bid & 7) << 7) | (bid >> 3);
  const int n   = L >> 5;                     // image (32 tiles of 128 cols)
  const int hw0 = (L & 31) << 7;              // 128-col tile
  const int wv  = t >> 6, lane = t & 63;
  const int g   = lane >> 4, lcol = lane & 15;

  const float* Xg = X + n * (DIM * HW) + hw0;
  const int db8 = t >> 5;                     // 0..7
  const int cp  = t & 31;                     // 0..31
  const int kss = db8 >> 2, gs = db8 & 3;

  for (int rep = 0; rep < 2; ++rep) {
    // ---- stage X tile fp32->bf16 straight into fragment order ------------
    f32x2 v[2][8];
    #pragma unroll
    for (int h = 0; h < 2; ++h)
      #pragma unroll
      for (int j = 0; j < 8; ++j)
        v[h][j] = __builtin_nontemporal_load(
            (const f32x2*)(Xg + (db8 * 8 + j) * HW + h * 64 + cp * 2));
    float sx2 = 0.f;
    #pragma unroll
    for (int h = 0; h < 2; ++h)
      #pragma unroll
      for (int j = 0; j < 8; ++j)
        sx2 += v[h][j].x * v[h][j].x + v[h][j].y * v[h][j].y;
    #pragma unroll
    for (int h = 0; h < 2; ++h) {
      #pragma unroll
      for (int ci = 0; ci < 2; ++ci) {
        const int cl   = cp * 2 + ci;         // 0..63 within half
        const int cb   = h * 4 + (cl >> 4);   // 0..7 col-block
        const int slot = (cb * 2 + kss) * 64 + gs * 16 + (cl & 15);
        const int swz  = slot ^ ((slot >> 3) & 7);
        short8 w;
        #pragma unroll
        for (int j = 0; j < 8; ++j)
          w[j] = (short)f2bf(ci ? v[h][j].y : v[h][j].x);
        *(short8*)&XF[swz * 8] = w;
      }
    }
    __syncthreads();

    // ---- B-frags from LDS: 16x ds_read_b128, conflict-free, resident -----
    const int swzl = lane ^ ((lane >> 3) & 7);
    short8 bfrag[2][4][2];
    #pragma unroll
    for (int h = 0; h < 2; ++h)
      #pragma unroll
      for (int cb2 = 0; cb2 < 4; ++cb2)
        #pragma unroll
        for (int ks = 0; ks < 2; ++ks)
          bfrag[h][cb2][ks] =
              *(const short8*)&XF[(((h * 4 + cb2) * 2 + ks) * 64 + swzl) * 8];

    // ---- this wave scans 128 codes = 8 chunks of 16, over all 128 cols ---
    float m1[8];
    #pragma unroll
    for (int cb = 0; cb < 8; ++cb) m1[cb] = 3.0e38f;

    const int chunk0 = wv * 8;
    #pragma unroll 2
    for (int i = 0; i < 8; ++i) {
      const int chunk = chunk0 + i;
      const short8 a0 = *(const short8*)&aFg[((chunk*2 + 0) * 64 + lane) * 8];
      const short8 a1 = *(const short8*)&aFg[((chunk*2 + 1) * 64 + lane) * 8];
      const int codebase = chunk * 16 + g * 4;
      const f32x4 cn = *(const f32x4*)&cng[codebase];
      #pragma unroll
      for (int h = 0; h < 2; ++h) {
        #pragma unroll
        for (int cb2 = 0; cb2 < 4; ++cb2) {
          f32x4 acc = cn;
          acc = __builtin_amdgcn_mfma_f32_16x16x32_bf16(a0, bfrag[h][cb2][0], acc, 0, 0, 0);
          acc = __builtin_amdgcn_mfma_f32_16x16x32_bf16(a1, bfrag[h][cb2][1], acc, 0, 0, 0);
          #pragma unroll
          for (int r = 0; r < 4; ++r) {
            unsigned int vb = __builtin_bit_cast(unsigned int, acc[r]);
            vb = (vb & 0xFFFFFE00u) | ((unsigned)(codebase + r) & 0x1FFu);
            m1[h * 4 + cb2] = fminf(m1[h * 4 + cb2], __builtin_bit_cast(float, vb));
          }
        }
      }
    }

    // combine lane-groups (disjoint code subsets, same col)
    #pragma unroll
    for (int cb = 0; cb < 8; ++cb) {
      m1[cb] = fminf(m1[cb], __shfl_xor(m1[cb], 16));
      m1[cb] = fminf(m1[cb], __shfl_xor(m1[cb], 32));
      if (g == 0) mW[wv][cb * 16 + lcol] = m1[cb];
    }
    __syncthreads();

    // ---- final per-col argmin + epilogue, two 64-col passes --------------
    float msum = 0.f;
    #pragma unroll
    for (int h = 0; h < 2; ++h) {
      const int c = h * 64 + lane;
      const float p = fminf(fminf(mW[0][c], mW[1][c]),
                            fminf(mW[2][c], mW[3][c]));
      const unsigned int b = __builtin_bit_cast(unsigned int, p);
      const int k = (int)(b & 511u);
      msum += __builtin_bit_cast(float, b & 0xFFFFFE00u);

      const float* cq = CB + k * DIM + wv * 16; // L2-hot gather
      float* op = out + 1 + n * (DIM * HW) + hw0 + c;
      #pragma unroll
      for (int i = 0; i < 4; ++i) {
        float4 u = *(const float4*)(cq + i * 4);
        __builtin_nontemporal_store(u.x, &op[(wv*16 + i*4 + 0) * HW]);
        __builtin_nontemporal_store(u.y, &op[(wv*16 + i*4 + 1) * HW]);
        __builtin_nontemporal_store(u.z, &op[(wv*16 + i*4 + 2) * HW]);
        __builtin_nontemporal_store(u.w, &op[(wv*16 + i*4 + 3) * HW]);
      }
    }

    // ---- loss partials (no atomics; vq_fin reduces) ----
    float w1 = wave_sum(sx2);
    if (lane == 0) red[wv] = w1;
    if (wv == 0) {
      float w2 = wave_sum(msum);              // each col counted once
      if (lane == 0) red[4] = w2;
    }
    __syncthreads();
    if (t == 0) {
      pA[bid] = red[0] + red[1] + red[2] + red[3];
      pB[bid] = red[4];
    }
    __syncthreads();                          // rep isolation (XF reuse)
  }
}

__global__ void vq_fin(const float* __restrict__ pA,
                       const float* __restrict__ pB,
                       float* __restrict__ out) {
  const int t = threadIdx.x;                  // 512 threads, 1024 partials
  f32x2 a = *(const f32x2*)&pA[t * 2];
  f32x2 c = *(const f32x2*)&pB[t * 2];
  float v = a.x + a.y + c.x + c.y;
  v = wave_sum(v);
  __shared__ float r[8];
  if ((t & 63) == 0) r[t >> 6] = v;
  __syncthreads();
  if (t == 0) {
    float s = 0.f;
    #pragma unroll
    for (int i = 0; i < 8; ++i) s += r[i];
    out[0] = 1.25f * s * (1.0f / NELEM);
  }
}

extern "C" void kernel_launch(void* const* d_in, const int* in_sizes, int n_in,
                              void* d_out, int out_size, void* d_ws, size_t ws_size,
                              hipStream_t stream) {
  const float* X  = (const float*)d_in[0];   // [32,64,64,64] fp32
  const float* CB = (const float*)d_in[1];   // [512,64] fp32
  float* out = (float*)d_out;                // [0]=loss, [1..]=quantized_st
  char* ws = (char*)d_ws;
  unsigned short* aFg = (unsigned short*)ws;
  float* cn = (float*)(ws + 65536);
  float* pA = (float*)(ws + 67584);
  float* pB = (float*)(ws + 75776);
  (void)in_sizes; (void)n_in; (void)out_size; (void)ws_size;

  vq_prep<<<8, 512, 0, stream>>>(CB, aFg, cn);
  vq_main<<<NBLK, 256, 0, stream>>>(X, CB, aFg, cn, out, pA, pB);
  vq_fin<<<1, 512, 0, stream>>>(pA, pB, out);
}

// Round 10
// 34.301 us; speedup vs baseline: 2.7992x; 2.7992x over previous
//
#include <hip/hip_runtime.h>

#define DIM 64
#define HW 4096          // 64*64
#define NELEM 8388608.0f // 32*64*4096
#define NBLK 256         // 512-col tiles, 1 block/CU

typedef __attribute__((ext_vector_type(8))) short short8;   // 8 x bf16
typedef __attribute__((ext_vector_type(4))) float f32x4;
typedef __attribute__((ext_vector_type(2))) float f32x2;

__device__ __forceinline__ unsigned short f2bf(float f) {
  unsigned int u = __builtin_bit_cast(unsigned int, f);
  u += 0x7fffu + ((u >> 16) & 1u);            // round-to-nearest-even
  return (unsigned short)(u >> 16);
}

__device__ __forceinline__ float wave_sum(float v) {
  #pragma unroll
  for (int off = 32; off >= 1; off >>= 1) v += __shfl_xor(v, off);
  return v;
}

// ws layout (bytes):
//  [0,      65536)  A-frags: bf16(-2*codebook), MFMA-fragment order (L2-hot)
//  [65536,  67584)  cnorm fp32 [512]
//  [67584,  68608)  per-block partial sum(x^2)      (256 floats)
//  [75776,  76800)  per-block partial sum(min d2')  (256 floats)

// ---------------- prep: codebook -> fragment order (once per call) ---------
__global__ void vq_prep(const float* __restrict__ CB,
                        unsigned short* __restrict__ aFg,
                        float* __restrict__ cn) {
  const int t = threadIdx.x;
  const int s = blockIdx.x * 512 + t;     // 0..4095 fragment slots
  const int chunk = s >> 7, ks = (s >> 6) & 1, ls = s & 63;
  const int code = chunk * 16 + (ls & 15);
  const int d0 = ks * 32 + (ls >> 4) * 8;
  const float* cp = CB + code * DIM + d0;
  float4 u0 = *(const float4*)cp;
  float4 u1 = *(const float4*)(cp + 4);
  short8 p;
  p[0]=(short)f2bf(-2.f*u0.x); p[1]=(short)f2bf(-2.f*u0.y);
  p[2]=(short)f2bf(-2.f*u0.z); p[3]=(short)f2bf(-2.f*u0.w);
  p[4]=(short)f2bf(-2.f*u1.x); p[5]=(short)f2bf(-2.f*u1.y);
  p[6]=(short)f2bf(-2.f*u1.z); p[7]=(short)f2bf(-2.f*u1.w);
  *(short8*)&aFg[s * 8] = p;
  if (blockIdx.x == 0) {                  // exact fp32 ||c_k||^2
    const float* c2 = CB + t * DIM;
    float sn = 0.f;
    #pragma unroll
    for (int i = 0; i < 16; ++i) {
      float4 u = *(const float4*)(c2 + i * 4);
      sn += u.x*u.x + u.y*u.y + u.z*u.z + u.w*u.w;
    }
    cn[t] = sn;
  }
}

// ---- main: 256 blocks x 8 waves; 512-col tile; codes split across waves ---
// R10: DRAM SEGMENT LENGTH test.  All prior variants touched X/out in
// 256-512B segments at 16KB stride (~45% DRAM eff ~ 2.3-2.8 TB/s observed);
// fills (contiguous) hit 6.4.  512-col tiles make every X-read and out-write
// segment 2KB:  loads  = per row, 4 consecutive 512B wave-loads (f32x2);
//               stores = per row, 8 consecutive 256B wave-stores.
// 256 blocks = exactly 1/CU (LDS 82KB).  8 waves x 64 codes.  All register
// arrays fully unrolled/static (R8 spill lesson: no partial-unroll pragmas).
// NO atomics/fences (same-addr device atomics ~100us convoy, prev session).
__global__ __launch_bounds__(512, 2)
void vq_main(const float* __restrict__ X, const float* __restrict__ CB,
             const unsigned short* __restrict__ aFg,
             const float* __restrict__ cng,
             float* __restrict__ out,
             float* __restrict__ pA, float* __restrict__ pB) {
  __shared__ __align__(16) unsigned short XF[64 * 64 * 8]; // 64 KB frag-order
  __shared__ float mW[8][512];                // 16 KB per-wave mins per col
  __shared__ float red[16];

  const int t   = threadIdx.x;
  const int bid = blockIdx.x;
  // XCD-chunked swizzle: XCD x owns logical blocks [x*32,(x+1)*32)
  const int L   = ((bid & 7) << 5) | (bid >> 3);
  const int n   = L >> 3;                     // image (8 tiles of 512 cols)
  const int hw0 = (L & 7) << 9;               // 512-col tile
  const int wv  = t >> 6, lane = t & 63;
  const int g   = lane >> 4, lcol = lane & 15;
  const int db8 = t >> 6;                     // row-group 0..7 (== wv)
  const int cs  = lane;                       // col-seed 0..63
  const int kss = db8 >> 2, gs = db8 & 3;

  const float* Xg = X + n * (DIM * HW) + hw0;

  // ---- stage X tile fp32->bf16 into fragment order -----------------------
  // thread: rows [db8*8,+8), cols {cs*2+ci + 128*q}.  Per (row j): 4
  // consecutive 512B wave-loads -> 2KB contiguous per row.
  f32x2 v[8][4];
  #pragma unroll
  for (int j = 0; j < 8; ++j)
    #pragma unroll
    for (int q = 0; q < 4; ++q)
      v[j][q] = __builtin_nontemporal_load(
          (const f32x2*)(Xg + (db8 * 8 + j) * HW + q * 128 + cs * 2));
  float sx2 = 0.f;
  #pragma unroll
  for (int j = 0; j < 8; ++j)
    #pragma unroll
    for (int q = 0; q < 4; ++q)
      sx2 += v[j][q].x * v[j][q].x + v[j][q].y * v[j][q].y;
  #pragma unroll
  for (int q = 0; q < 4; ++q) {
    #pragma unroll
    for (int ci = 0; ci < 2; ++ci) {
      const int c    = q * 128 + cs * 2 + ci; // 0..511
      const int cb   = c >> 4;                // 0..31 col-block
      const int slot = (cb * 2 + kss) * 64 + gs * 16 + (c & 15);
      const int swz  = slot ^ ((slot >> 3) & 7);
      short8 w;
      #pragma unroll
      for (int j = 0; j < 8; ++j)
        w[j] = (short)f2bf(ci ? v[j][q].y : v[j][q].x);
      *(short8*)&XF[swz * 8] = w;
    }
  }
  __syncthreads();

  // ---- compute: this wave scans 64 codes (4 chunks) over all 512 cols ----
  const int swzl = lane ^ ((lane >> 3) & 7);
  f32x4 cnq[4];                               // hoisted ||c||^2 quads
  #pragma unroll
  for (int i = 0; i < 4; ++i)
    cnq[i] = *(const f32x4*)&cng[(wv * 4 + i) * 16 + g * 4];

  #pragma unroll 1
  for (int cg = 0; cg < 8; ++cg) {            // 8 col-groups of 64
    short8 bfrag[4][2];
    #pragma unroll
    for (int cb2 = 0; cb2 < 4; ++cb2)
      #pragma unroll
      for (int ks = 0; ks < 2; ++ks)
        bfrag[cb2][ks] =
            *(const short8*)&XF[(((cg * 4 + cb2) * 2 + ks) * 64 + swzl) * 8];

    float m1[4];
    #pragma unroll
    for (int cb2 = 0; cb2 < 4; ++cb2) m1[cb2] = 3.0e38f;

    #pragma unroll
    for (int i = 0; i < 4; ++i) {
      const int chunk = wv * 4 + i;
      const short8 a0 = *(const short8*)&aFg[((chunk*2 + 0) * 64 + lane) * 8];
      const short8 a1 = *(const short8*)&aFg[((chunk*2 + 1) * 64 + lane) * 8];
      const int codebase = chunk * 16 + g * 4;
      #pragma unroll
      for (int cb2 = 0; cb2 < 4; ++cb2) {
        f32x4 acc = cnq[i];
        acc = __builtin_amdgcn_mfma_f32_16x16x32_bf16(a0, bfrag[cb2][0], acc, 0, 0, 0);
        acc = __builtin_amdgcn_mfma_f32_16x16x32_bf16(a1, bfrag[cb2][1], acc, 0, 0, 0);
        #pragma unroll
        for (int r = 0; r < 4; ++r) {
          unsigned int vb = __builtin_bit_cast(unsigned int, acc[r]);
          vb = (vb & 0xFFFFFE00u) | ((unsigned)(codebase + r) & 0x1FFu);
          m1[cb2] = fminf(m1[cb2], __builtin_bit_cast(float, vb));
        }
      }
    }
    #pragma unroll
    for (int cb2 = 0; cb2 < 4; ++cb2) {
      m1[cb2] = fminf(m1[cb2], __shfl_xor(m1[cb2], 16));
      m1[cb2] = fminf(m1[cb2], __shfl_xor(m1[cb2], 32));
      if (g == 0) mW[wv][cg * 64 + cb2 * 16 + lcol] = m1[cb2];
    }
  }
  __syncthreads();

  // ---- final per-col argmin over the 8 wave code-subsets -----------------
  float msum = 0.f;
  const float* cqp[8];
  #pragma unroll
  for (int hh = 0; hh < 8; ++hh) {
    const int c = hh * 64 + lane;
    float p = fminf(fminf(mW[0][c], mW[1][c]), fminf(mW[2][c], mW[3][c]));
    p = fminf(p, fminf(fminf(mW[4][c], mW[5][c]), fminf(mW[6][c], mW[7][c])));
    const unsigned int b = __builtin_bit_cast(unsigned int, p);
    const int k = (int)(b & 511u);
    msum += __builtin_bit_cast(float, b & 0xFFFFFE00u);
    cqp[hh] = CB + k * DIM + wv * 8;          // this wave's 8 d-rows
  }

  // ---- epilogue: wave wv writes rows [wv*8,+8); per row, 8 consecutive
  //      256B wave-stores -> 2KB contiguous runs ---------------------------
  float* opb = out + 1 + n * (DIM * HW) + hw0 + lane;
  #pragma unroll
  for (int i = 0; i < 2; ++i) {
    f32x4 U[8];
    #pragma unroll
    for (int hh = 0; hh < 8; ++hh)
      U[hh] = *(const f32x4*)(cqp[hh] + i * 4); // L2-hot gather
    #pragma unroll
    for (int rr = 0; rr < 4; ++rr) {
      float* op = opb + (wv * 8 + i * 4 + rr) * HW;
      #pragma unroll
      for (int hh = 0; hh < 8; ++hh)
        __builtin_nontemporal_store(U[hh][rr], &op[hh * 64]);
    }
  }

  // ---- loss partials (no atomics; vq_fin reduces) ----
  float w1 = wave_sum(sx2);
  if (lane == 0) red[wv] = w1;
  if (wv == 0) {
    float w2 = wave_sum(msum);                // each col counted once
    if (lane == 0) red[8] = w2;
  }
  __syncthreads();
  if (t == 0) {
    float s = 0.f;
    #pragma unroll
    for (int i = 0; i < 8; ++i) s += red[i];
    pA[bid] = s;
    pB[bid] = red[8];
  }
}

__global__ void vq_fin(const float* __restrict__ pA,
                       const float* __restrict__ pB,
                       float* __restrict__ out) {
  const int t = threadIdx.x;                  // 256 threads, 256 partials
  float v = pA[t] + pB[t];
  v = wave_sum(v);
  __shared__ float r[4];
  if ((t & 63) == 0) r[t >> 6] = v;
  __syncthreads();
  if (t == 0)
    out[0] = 1.25f * (r[0] + r[1] + r[2] + r[3]) * (1.0f / NELEM);
}

extern "C" void kernel_launch(void* const* d_in, const int* in_sizes, int n_in,
                              void* d_out, int out_size, void* d_ws, size_t ws_size,
                              hipStream_t stream) {
  const float* X  = (const float*)d_in[0];   // [32,64,64,64] fp32
  const float* CB = (const float*)d_in[1];   // [512,64] fp32
  float* out = (float*)d_out;                // [0]=loss, [1..]=quantized_st
  char* ws = (char*)d_ws;
  unsigned short* aFg = (unsigned short*)ws;
  float* cn = (float*)(ws + 65536);
  float* pA = (float*)(ws + 67584);
  float* pB = (float*)(ws + 75776);
  (void)in_sizes; (void)n_in; (void)out_size; (void)ws_size;

  vq_prep<<<8, 512, 0, stream>>>(CB, aFg, cn);
  vq_main<<<NBLK, 512, 0, stream>>>(X, CB, aFg, cn, out, pA, pB);
  vq_fin<<<1, 256, 0, stream>>>(pA, pB, out);
}